// Round 8
// baseline (131.303 us; speedup 1.0000x reference)
//
#include <hip/hip_runtime.h>
#include <hip/hip_bf16.h>
#include <math.h>

#define BATCH 128
#define NNODE 512
#define RU 64
#define MEM_DIM 16
#define BOT_DIM 4
#define IN_SZ 66
#define OUT_SZ 256
#define HID (NNODE*RU)          // 32768
#define W3_ROW 16896            // IN_SZ*OUT_SZ
// Wc layout: per node, 48 frags (f = ct*3+ks, ct in [0,16), ks in [0,3)),
// each frag 512 bf16 = lane*8+j. col o = (ct&3)*64+(ct>>2)*16+(lane&15);
// slot s = ks*32+(lane>>4)*8+j ; s<64 -> W row i=s+2 ; s=64,65 -> i=0,1 ; else 0.
#define NODE_WC 24576           // shorts per node (48*512); 49152 B
#define HALF_WC 12288           // shorts per half (24 frags)

typedef __attribute__((ext_vector_type(8))) short short8;
typedef __attribute__((ext_vector_type(4))) float float4v;

__device__ __forceinline__ unsigned pack2(float x, float y) {
    union { __hip_bfloat162 h; unsigned u; } cv;
    cv.h = __float22bfloat162_rn(make_float2(x, y));
    return cv.u;
}
__device__ __forceinline__ float fsig(float x) {
    return __builtin_amdgcn_rcpf(1.0f + __expf(-x));
}
__device__ __forceinline__ float ftanh(float x) {
    return 1.0f - 2.0f * __builtin_amdgcn_rcpf(1.0f + __expf(2.0f * x));
}

// ---------------- Kernel 1: combined-W stream (hypernet folded in) -----------
// block = (fp: frag-pair [0,24)) x (ng: 16-node group [0,32)) = 768 blocks.
// Stage 2 frags x 5 matrices of w3/b3 (20KB LDS), hypernet for 16 nodes,
// then stream 16 nodes x 8B/thread contiguous bf16 stores.
__global__ __launch_bounds__(256) void wcomb_kernel(
    const float* __restrict__ memory, const float* __restrict__ w1,
    const float* __restrict__ b1,     const float* __restrict__ w2,
    const float* __restrict__ b2,     const float* __restrict__ w3,
    const float* __restrict__ b3,     unsigned short* __restrict__ Wc)
{
    __shared__ alignas(16) float w5s[2][5][512];   // 20480 B
    __shared__ float mem1s[16][MEM_DIM];
    __shared__ float m2s[16][BOT_DIM];

    const int tid = threadIdx.x;
    const unsigned bid = blockIdx.x;
    const int fp = bid >> 5;          // [0,24)
    const int ng = bid & 31;          // [0,32)

    // ---- stage w3_0..3 + b3 fragments (frag-permuted, one-time, L2-hot) ----
    for (int e = tid; e < 5120; e += 256) {
        const int fl  = e / 2560;
        const int k   = (e - fl * 2560) >> 9;   // [0,5)
        const int idx = e & 511;
        const int l = idx >> 3, j = idx & 7;
        const int f  = fp * 2 + fl;
        const int ks = f % 3;
        const int ct = f / 3;
        const int q = l & 15, quad = l >> 4;
        const int o = (ct & 3) * 64 + (ct >> 2) * 16 + q;
        const int s = ks * 32 + quad * 8 + j;
        float v = 0.f;
        if (s < IN_SZ) {
            const int i = (s < 64) ? s + 2 : s - 64;
            v = (k < 4) ? w3[k * W3_ROW + i * OUT_SZ + o] : b3[i * OUT_SZ + o];
        }
        w5s[fl][k][idx] = v;
    }

    // ---- hypernet for this block's 16 nodes ----
    {
        const int nn = tid >> 4, t = tid & 15;
        float s = b1[t];
        #pragma unroll
        for (int j = 0; j < MEM_DIM; ++j)
            s += memory[(ng * 16 + nn) * MEM_DIM + j] * w1[j * MEM_DIM + t];
        mem1s[nn][t] = ftanh(s);
    }
    __syncthreads();
    if (tid < 64) {
        const int nn = tid >> 2, t4 = tid & 3;
        float s = b2[t4];
        #pragma unroll
        for (int j = 0; j < MEM_DIM; ++j)
            s += mem1s[nn][j] * w2[j * BOT_DIM + t4];
        m2s[nn][t4] = ftanh(s);
    }
    __syncthreads();

    // ---- hoist this thread's 5 weight float4s, then stream 16 nodes ----
    const int fl   = tid >> 7;            // 0/1
    const int idx4 = (tid & 127) * 4;
    const float4v wk0 = *(const float4v*)&w5s[fl][0][idx4];
    const float4v wk1 = *(const float4v*)&w5s[fl][1][idx4];
    const float4v wk2 = *(const float4v*)&w5s[fl][2][idx4];
    const float4v wk3 = *(const float4v*)&w5s[fl][3][idx4];
    const float4v wb  = *(const float4v*)&w5s[fl][4][idx4];

    unsigned short* base = Wc + (size_t)(ng * 16) * NODE_WC
                         + (fp * 2 + fl) * 512 + idx4;
    #pragma unroll 4
    for (int nn = 0; nn < 16; ++nn) {
        float4v r = wb + m2s[nn][0] * wk0 + m2s[nn][1] * wk1
                       + m2s[nn][2] * wk2 + m2s[nn][3] * wk3;
        uint2 p;
        p.x = pack2(r[0], r[1]);
        p.y = pack2(r[2], r[3]);
        *(uint2*)(base + (size_t)nn * NODE_WC) = p;   // contiguous 8B across tid
    }
}

// ---------------- Kernel 2: MFMA GEMM + LSTM epilogue ------------------------
// block = (n, h): 1024 blocks. W half-tile via global_load_lds DMA (zero VALU),
// A packed once from hx/inputs, one barrier, 48 MFMA/wave, in-register epilogue.
__global__ __launch_bounds__(256) void gemm_kernel(
    const float* __restrict__ inputs, const float* __restrict__ hx,
    const float* __restrict__ cx,     const float* __restrict__ b_out,
    const unsigned short* __restrict__ Wc, float* __restrict__ out)
{
    __shared__ unsigned short Wl[HALF_WC];   // 24576 B, frag order
    const int tid  = threadIdx.x;
    const unsigned bid = blockIdx.x;
    const int n    = bid >> 1;
    const int h    = bid & 1;
    const int w    = tid >> 6;
    const int lane = tid & 63;
    const int q    = lane & 15;
    const int quad = lane >> 4;

    // 1. async DMA the 24 KB W half-tile (24 x 1KB wave-insts)
    const unsigned short* gW = Wc + (size_t)n * NODE_WC + h * HALF_WC;
    for (int t = w; t < 24; t += 4) {
        __builtin_amdgcn_global_load_lds(
            (__attribute__((address_space(1))) void*)(gW + t * 512 + lane * 8),
            (__attribute__((address_space(3))) void*)(Wl + t * 512),
            16, 0, 0);
    }

    // 2. A fragments + epilogue operands while DMA is in flight
    float4v xa[2][4];
    float xin[2][2];
    #pragma unroll
    for (int rt = 0; rt < 2; ++rt) {
        const int row = w * 32 + rt * 16 + q;
        const float* hrow = hx + (size_t)row * HID + n * RU + quad * 8;
        xa[rt][0] = *(const float4v*)(hrow);
        xa[rt][1] = *(const float4v*)(hrow + 4);
        xa[rt][2] = *(const float4v*)(hrow + 32);
        xa[rt][3] = *(const float4v*)(hrow + 36);
        if (quad == 0) {
            const float* ip = inputs + (size_t)row * (NNODE * 2) + n * 2;
            xin[rt][0] = ip[0];
            xin[rt][1] = ip[1];
        } else {
            xin[rt][0] = 0.f;
            xin[rt][1] = 0.f;
        }
    }

    float bo[2][4];
    #pragma unroll
    for (int rh = 0; rh < 2; ++rh)
        #pragma unroll
        for (int g = 0; g < 4; ++g)
            bo[rh][g] = b_out[g * 64 + (h * 2 + rh) * 16 + q];

    float cxr[2][4][2];
    #pragma unroll
    for (int rt = 0; rt < 2; ++rt)
        #pragma unroll
        for (int v = 0; v < 4; ++v) {
            const int b = w * 32 + rt * 16 + quad * 4 + v;
            #pragma unroll
            for (int rh = 0; rh < 2; ++rh)
                cxr[rt][v][rh] = cx[(size_t)b * HID + n * RU + (h * 2 + rh) * 16 + q];
        }

    // pack A once (bf16, RNE)
    short8 a[3][2];
    #pragma unroll
    for (int rt = 0; rt < 2; ++rt) {
        #pragma unroll
        for (int ksh = 0; ksh < 2; ++ksh) {
            float4v lo = xa[rt][ksh * 2];
            float4v hi = xa[rt][ksh * 2 + 1];
            union { short8 s; unsigned u[4]; } t;
            t.u[0] = pack2(lo[0], lo[1]);
            t.u[1] = pack2(lo[2], lo[3]);
            t.u[2] = pack2(hi[0], hi[1]);
            t.u[3] = pack2(hi[2], hi[3]);
            a[ksh][rt] = t.s;
        }
        union { short8 s; unsigned u[4]; } t2;
        t2.u[0] = pack2(xin[rt][0], xin[rt][1]);
        t2.u[1] = t2.u[2] = t2.u[3] = 0u;
        a[2][rt] = t2.s;
    }

    float4v acc[2][8];
    #pragma unroll
    for (int rt = 0; rt < 2; ++rt)
        #pragma unroll
        for (int ctl = 0; ctl < 8; ++ctl)
            acc[rt][ctl] = (float4v){0.f, 0.f, 0.f, 0.f};

    __syncthreads();   // drains DMA + barrier

    // 3. MFMA: 3 ks x 8 ctl x 2 rt
    #pragma unroll
    for (int ks = 0; ks < 3; ++ks) {
        #pragma unroll
        for (int ctl = 0; ctl < 8; ++ctl) {
            short8 bf = *(const short8*)(Wl + (ctl * 3 + ks) * 512 + lane * 8);
            acc[0][ctl] = __builtin_amdgcn_mfma_f32_16x16x32_bf16(a[ks][0], bf, acc[0][ctl], 0, 0, 0);
            acc[1][ctl] = __builtin_amdgcn_mfma_f32_16x16x32_bf16(a[ks][1], bf, acc[1][ctl], 0, 0, 0);
        }
    }

    // 4. LSTM epilogue: ctl = rh*4+g -> o = g*64 + (h*2+rh)*16 + q
    #pragma unroll
    for (int rt = 0; rt < 2; ++rt) {
        #pragma unroll
        for (int v = 0; v < 4; ++v) {
            const int b = w * 32 + rt * 16 + quad * 4 + v;
            const size_t base = (size_t)b * HID + n * RU;
            #pragma unroll
            for (int rh = 0; rh < 2; ++rh) {
                // reference: val = sigmoid(matmul) + b_out, THEN gate activations
                float vi = fsig(acc[rt][rh * 4 + 0][v]) + bo[rh][0];
                float vf = fsig(acc[rt][rh * 4 + 1][v]) + bo[rh][1];
                float vg = fsig(acc[rt][rh * 4 + 2][v]) + bo[rh][2];
                float vo = fsig(acc[rt][rh * 4 + 3][v]) + bo[rh][3];
                float it = fsig(vi), ft = fsig(vf);
                float gt = ftanh(vg), ot = fsig(vo);
                const size_t idx = base + (h * 2 + rh) * 16 + q;
                float cc = cxr[rt][v][rh] * ft + it * gt;
                out[idx] = ot * ftanh(cc);               // hy
                out[(size_t)BATCH * HID + idx] = cc;     // cy
            }
        }
    }
}

extern "C" void kernel_launch(void* const* d_in, const int* in_sizes, int n_in,
                              void* d_out, int out_size, void* d_ws, size_t ws_size,
                              hipStream_t stream) {
    const float* inputs = (const float*)d_in[0];
    const float* hx     = (const float*)d_in[1];
    const float* cx     = (const float*)d_in[2];
    const float* memory = (const float*)d_in[3];
    const float* w1     = (const float*)d_in[4];
    const float* b1     = (const float*)d_in[5];
    const float* w2     = (const float*)d_in[6];
    const float* b2     = (const float*)d_in[7];
    const float* w3     = (const float*)d_in[8];
    const float* b3     = (const float*)d_in[9];
    const float* b_out  = (const float*)d_in[10];
    float* out = (float*)d_out;

    unsigned short* Wc = (unsigned short*)d_ws;   // 25.2 MB

    wcomb_kernel<<<24 * 32, 256, 0, stream>>>(memory, w1, b1, w2, b2, w3, b3, Wc);
    gemm_kernel<<<NNODE * 2, 256, 0, stream>>>(inputs, hx, cx, b_out, Wc, out);
}

// Round 9
// 122.149 us; speedup vs baseline: 1.0749x; 1.0749x over previous
//
#include <hip/hip_runtime.h>
#include <math.h>

#define BATCH 128
#define NNODE 512
#define RU 64
#define MEM_DIM 16
#define BOT_DIM 4
#define IN_SZ 66
#define OUT_SZ 256
#define HID (NNODE*RU)          // 32768
#define W3_ROW 16896            // IN_SZ*OUT_SZ
// fp16 frag table: frag f = k*48 + h*24 + fl, fl = ctl*3+ks (ct = h*8+ctl);
// element = lane*8+j. col o = (ct&3)*64+(ct>>2)*16+(lane&15);
// slot s = ks*32+(lane>>4)*8+j ; s<64 -> W row i=s+2 ; s=64,65 -> i=0,1 ; else 0.
#define TAB_HALVES (240*512)    // 122880 halves = 245760 B
#define KSTEP (48*512)          // halves between k-matrices

typedef _Float16 half8 __attribute__((ext_vector_type(8)));
typedef __attribute__((ext_vector_type(4))) float float4v;

__device__ __forceinline__ float fsig(float x) {
    return __builtin_amdgcn_rcpf(1.0f + __expf(-x));
}
__device__ __forceinline__ float ftanh(float x) {
    return 1.0f - 2.0f * __builtin_amdgcn_rcpf(1.0f + __expf(2.0f * x));
}

// ---------------- Kernel 1: prep — fp16 frag table + hypernet m2 --------------
__global__ __launch_bounds__(256) void prep_kernel(
    const float* __restrict__ memory, const float* __restrict__ w1,
    const float* __restrict__ b1,     const float* __restrict__ w2,
    const float* __restrict__ b2,     const float* __restrict__ w3,
    const float* __restrict__ b3,     _Float16* __restrict__ tab,
    float* __restrict__ m2_ws)
{
    const int tid = threadIdx.x;
    const int bid = blockIdx.x;
    if (bid < 60) {
        const int c = bid * 256 + tid;      // chunk [0,15360)
        const int f = c >> 6;               // frag [0,240)
        const int l = c & 63;
        const int k   = f / 48;             // [0,5): w3 rows 0..3, then b3
        const int rem = f - k * 48;         // = ct*3 + ks, ct = h*8+ctl
        const int ct  = rem / 3;
        const int ks  = rem - ct * 3;
        const int q = l & 15, quad = l >> 4;
        const int o = (ct & 3) * 64 + (ct >> 2) * 16 + q;
        const float* src = (k < 4) ? (w3 + k * W3_ROW) : b3;
        half8 v;
        #pragma unroll
        for (int j = 0; j < 8; ++j) {
            const int s = ks * 32 + quad * 8 + j;
            float x = 0.f;
            if (s < IN_SZ) {
                const int i = (s < 64) ? s + 2 : s - 64;
                x = src[i * OUT_SZ + o];
            }
            v[j] = (_Float16)x;
        }
        *(half8*)(tab + f * 512 + l * 8) = v;
    } else {
        const int n = (bid - 60) * 256 + tid;   // [0,512)
        if (n < NNODE) {
            float memv[MEM_DIM];
            #pragma unroll
            for (int j = 0; j < MEM_DIM; ++j) memv[j] = memory[n * MEM_DIM + j];
            float mem1[MEM_DIM];
            #pragma unroll
            for (int t = 0; t < MEM_DIM; ++t) {
                float s = b1[t];
                #pragma unroll
                for (int j = 0; j < MEM_DIM; ++j) s += memv[j] * w1[j * MEM_DIM + t];
                mem1[t] = ftanh(s);
            }
            #pragma unroll
            for (int t = 0; t < BOT_DIM; ++t) {
                float s = b2[t];
                #pragma unroll
                for (int j = 0; j < MEM_DIM; ++j) s += mem1[j] * w2[j * BOT_DIM + t];
                m2_ws[n * 4 + t] = ftanh(s);
            }
        }
    }
}

// ---------------- Kernel 2: fused — per-node block, h=0/1 pipelined -----------
// grid 512 (block = node), 256 thr (4 waves x 32 batch rows). Double-buffered
// combined-W in LDS (fp16, pk_fma combine). A loaded once, reused for both h.
// Stores of h0 deferred past the 2nd barrier (no vmcnt-store drain at barrier).
__global__ __launch_bounds__(256) void fused_kernel(
    const float* __restrict__ inputs, const float* __restrict__ hx,
    const float* __restrict__ cx,     const float* __restrict__ b_out,
    const _Float16* __restrict__ tab, const float* __restrict__ m2_ws,
    float* __restrict__ out)
{
    __shared__ _Float16 Wl[2][24 * 512];   // 2 x 24576 B
    const int tid  = threadIdx.x;
    const int n    = blockIdx.x;
    const int w    = tid >> 6;
    const int lane = tid & 63;
    const int q    = lane & 15;
    const int quad = lane >> 4;

    // coef splat (fp16 for pk_fma combine)
    const float4v m2v = *(const float4v*)(m2_ws + n * 4);
    half8 vc[4];
    #pragma unroll
    for (int k = 0; k < 4; ++k) {
        const _Float16 c = (_Float16)m2v[k];
        vc[k] = (half8){c, c, c, c, c, c, c, c};
    }

    // ---- A loads (once, shared across both h) ----
    float4v xa[2][4];
    float xin[2][2];
    #pragma unroll
    for (int rt = 0; rt < 2; ++rt) {
        const int row = w * 32 + rt * 16 + q;
        const float* hrow = hx + (size_t)row * HID + n * RU + quad * 8;
        xa[rt][0] = *(const float4v*)(hrow);
        xa[rt][1] = *(const float4v*)(hrow + 4);
        xa[rt][2] = *(const float4v*)(hrow + 32);
        xa[rt][3] = *(const float4v*)(hrow + 36);
        if (quad == 0) {
            const float* ip = inputs + (size_t)row * (NNODE * 2) + n * 2;
            xin[rt][0] = ip[0];
            xin[rt][1] = ip[1];
        } else {
            xin[rt][0] = 0.f;
            xin[rt][1] = 0.f;
        }
    }

    // b_out for both halves: bo[h][rh][g]
    float bo[2][2][4];
    #pragma unroll
    for (int h = 0; h < 2; ++h)
        #pragma unroll
        for (int rh = 0; rh < 2; ++rh)
            #pragma unroll
            for (int g = 0; g < 4; ++g)
                bo[h][rh][g] = b_out[g * 64 + (h * 2 + rh) * 16 + q];

    // cx for h=0
    float cx0[2][4][2];
    #pragma unroll
    for (int rt = 0; rt < 2; ++rt)
        #pragma unroll
        for (int v = 0; v < 4; ++v) {
            const int b = w * 32 + rt * 16 + quad * 4 + v;
            #pragma unroll
            for (int rh = 0; rh < 2; ++rh)
                cx0[rt][v][rh] = cx[(size_t)b * HID + n * RU + rh * 16 + q];
        }

    // ---- combine h=0 -> buf0 (fp16 pk_fma) ----
    #pragma unroll
    for (int it = 0; it < 6; ++it) {
        const int c  = it * 256 + tid;
        const int fl = c >> 6;
        const int l  = c & 63;
        const _Float16* p = tab + (0 * 24 + fl) * 512 + l * 8;
        half8 r = *(const half8*)(p + 4 * KSTEP);     // b3 frag
        r += vc[0] * *(const half8*)(p);
        r += vc[1] * *(const half8*)(p + KSTEP);
        r += vc[2] * *(const half8*)(p + 2 * KSTEP);
        r += vc[3] * *(const half8*)(p + 3 * KSTEP);
        *(half8*)(&Wl[0][fl * 512 + l * 8]) = r;
    }

    // ---- pack A to fp16 once ----
    half8 a[3][2];
    #pragma unroll
    for (int rt = 0; rt < 2; ++rt) {
        #pragma unroll
        for (int ksh = 0; ksh < 2; ++ksh) {
            const float4v lo = xa[rt][ksh * 2];
            const float4v hi = xa[rt][ksh * 2 + 1];
            half8 t;
            t[0] = (_Float16)lo[0]; t[1] = (_Float16)lo[1];
            t[2] = (_Float16)lo[2]; t[3] = (_Float16)lo[3];
            t[4] = (_Float16)hi[0]; t[5] = (_Float16)hi[1];
            t[6] = (_Float16)hi[2]; t[7] = (_Float16)hi[3];
            a[ksh][rt] = t;
        }
        half8 t2 = (half8){0, 0, 0, 0, 0, 0, 0, 0};
        t2[0] = (_Float16)xin[rt][0];
        t2[1] = (_Float16)xin[rt][1];
        a[2][rt] = t2;
    }

    float4v acc[2][8];
    #pragma unroll
    for (int rt = 0; rt < 2; ++rt)
        #pragma unroll
        for (int ctl = 0; ctl < 8; ++ctl)
            acc[rt][ctl] = (float4v){0.f, 0.f, 0.f, 0.f};

    __syncthreads();

    // ---- MFMA h=0 ----
    #pragma unroll
    for (int ks = 0; ks < 3; ++ks)
        #pragma unroll
        for (int ctl = 0; ctl < 8; ++ctl) {
            const half8 bf = *(const half8*)(&Wl[0][(ctl * 3 + ks) * 512 + lane * 8]);
            acc[0][ctl] = __builtin_amdgcn_mfma_f32_16x16x32_f16(a[ks][0], bf, acc[0][ctl], 0, 0, 0);
            acc[1][ctl] = __builtin_amdgcn_mfma_f32_16x16x32_f16(a[ks][1], bf, acc[1][ctl], 0, 0, 0);
        }

    // ---- combine h=1 -> buf1 (loads overlap h0 epilogue compute) ----
    #pragma unroll
    for (int it = 0; it < 6; ++it) {
        const int c  = it * 256 + tid;
        const int fl = c >> 6;
        const int l  = c & 63;
        const _Float16* p = tab + (24 + fl) * 512 + l * 8;
        half8 r = *(const half8*)(p + 4 * KSTEP);
        r += vc[0] * *(const half8*)(p);
        r += vc[1] * *(const half8*)(p + KSTEP);
        r += vc[2] * *(const half8*)(p + 2 * KSTEP);
        r += vc[3] * *(const half8*)(p + 3 * KSTEP);
        *(half8*)(&Wl[1][fl * 512 + l * 8]) = r;
    }

    // cx for h=1 (L3-hot)
    float cx1[2][4][2];
    #pragma unroll
    for (int rt = 0; rt < 2; ++rt)
        #pragma unroll
        for (int v = 0; v < 4; ++v) {
            const int b = w * 32 + rt * 16 + quad * 4 + v;
            #pragma unroll
            for (int rh = 0; rh < 2; ++rh)
                cx1[rt][v][rh] = cx[(size_t)b * HID + n * RU + 32 + rh * 16 + q];
        }

    // ---- epilogue h=0: compute only, stores deferred past barrier ----
    float hy0[2][4][2], cy0[2][4][2];
    #pragma unroll
    for (int rt = 0; rt < 2; ++rt)
        #pragma unroll
        for (int v = 0; v < 4; ++v)
            #pragma unroll
            for (int rh = 0; rh < 2; ++rh) {
                // reference: val = sigmoid(matmul) + b_out, THEN gate activations
                float vi = fsig(acc[rt][rh * 4 + 0][v]) + bo[0][rh][0];
                float vf = fsig(acc[rt][rh * 4 + 1][v]) + bo[0][rh][1];
                float vg = fsig(acc[rt][rh * 4 + 2][v]) + bo[0][rh][2];
                float vo = fsig(acc[rt][rh * 4 + 3][v]) + bo[0][rh][3];
                float it = fsig(vi), ft = fsig(vf);
                float gt = ftanh(vg), ot = fsig(vo);
                float cc = cx0[rt][v][rh] * ft + it * gt;
                hy0[rt][v][rh] = ot * ftanh(cc);
                cy0[rt][v][rh] = cc;
            }

    // zero acc for h=1
    #pragma unroll
    for (int rt = 0; rt < 2; ++rt)
        #pragma unroll
        for (int ctl = 0; ctl < 8; ++ctl)
            acc[rt][ctl] = (float4v){0.f, 0.f, 0.f, 0.f};

    __syncthreads();

    // ---- stores h=0 (now, so barrier above never waited on them) ----
    #pragma unroll
    for (int rt = 0; rt < 2; ++rt)
        #pragma unroll
        for (int v = 0; v < 4; ++v) {
            const int b = w * 32 + rt * 16 + quad * 4 + v;
            const size_t base = (size_t)b * HID + n * RU;
            #pragma unroll
            for (int rh = 0; rh < 2; ++rh) {
                const size_t idx = base + rh * 16 + q;
                out[idx] = hy0[rt][v][rh];
                out[(size_t)BATCH * HID + idx] = cy0[rt][v][rh];
            }
        }

    // ---- MFMA h=1 ----
    #pragma unroll
    for (int ks = 0; ks < 3; ++ks)
        #pragma unroll
        for (int ctl = 0; ctl < 8; ++ctl) {
            const half8 bf = *(const half8*)(&Wl[1][(ctl * 3 + ks) * 512 + lane * 8]);
            acc[0][ctl] = __builtin_amdgcn_mfma_f32_16x16x32_f16(a[ks][0], bf, acc[0][ctl], 0, 0, 0);
            acc[1][ctl] = __builtin_amdgcn_mfma_f32_16x16x32_f16(a[ks][1], bf, acc[1][ctl], 0, 0, 0);
        }

    // ---- epilogue h=1 + stores ----
    #pragma unroll
    for (int rt = 0; rt < 2; ++rt)
        #pragma unroll
        for (int v = 0; v < 4; ++v) {
            const int b = w * 32 + rt * 16 + quad * 4 + v;
            const size_t base = (size_t)b * HID + n * RU;
            #pragma unroll
            for (int rh = 0; rh < 2; ++rh) {
                float vi = fsig(acc[rt][rh * 4 + 0][v]) + bo[1][rh][0];
                float vf = fsig(acc[rt][rh * 4 + 1][v]) + bo[1][rh][1];
                float vg = fsig(acc[rt][rh * 4 + 2][v]) + bo[1][rh][2];
                float vo = fsig(acc[rt][rh * 4 + 3][v]) + bo[1][rh][3];
                float it = fsig(vi), ft = fsig(vf);
                float gt = ftanh(vg), ot = fsig(vo);
                float cc = cx1[rt][v][rh] * ft + it * gt;
                const size_t idx = base + 32 + rh * 16 + q;
                out[idx] = ot * ftanh(cc);               // hy
                out[(size_t)BATCH * HID + idx] = cc;     // cy
            }
        }
}

extern "C" void kernel_launch(void* const* d_in, const int* in_sizes, int n_in,
                              void* d_out, int out_size, void* d_ws, size_t ws_size,
                              hipStream_t stream) {
    const float* inputs = (const float*)d_in[0];
    const float* hx     = (const float*)d_in[1];
    const float* cx     = (const float*)d_in[2];
    const float* memory = (const float*)d_in[3];
    const float* w1     = (const float*)d_in[4];
    const float* b1     = (const float*)d_in[5];
    const float* w2     = (const float*)d_in[6];
    const float* b2     = (const float*)d_in[7];
    const float* w3     = (const float*)d_in[8];
    const float* b3     = (const float*)d_in[9];
    const float* b_out  = (const float*)d_in[10];
    float* out = (float*)d_out;

    _Float16* tab = (_Float16*)d_ws;                      // 245760 B
    float* m2_ws  = (float*)((char*)d_ws + TAB_HALVES * 2);

    prep_kernel<<<62, 256, 0, stream>>>(memory, w1, b1, w2, b2, w3, b3, tab, m2_ws);
    fused_kernel<<<NNODE, 256, 0, stream>>>(inputs, hx, cx, b_out, tab, m2_ws, out);
}